// Round 1
// baseline (35172.568 us; speedup 1.0000x reference)
//
#include <hip/hip_runtime.h>
#include <math.h>

// ---------------------------------------------------------------------------
// Qwen2.5-Vision block on MI355X — round 1: correct fp32 implementation.
// S=2304 tokens, HID=1280, 16 heads x 80, 8 layers, window(64)/full attn,
// SwiGLU MLP (3420), final 2x2-merge MLP 5120->5120(gelu)->3584.
// T,H,W are fixed (1,48,48) by setup_inputs; permutations are closed-form.
// ---------------------------------------------------------------------------

#define N_TOK 2304

// perm-order block id for final-order block j  (win[j])
__device__ __forceinline__ int win_of(int j) {
    int iw  = j & 3;
    int ih  = (j >> 2) & 3;
    int gwo = (j >> 4) % 6;
    int go  = j / 96;
    return (go * 4 + ih) * 24 + (gwo * 4 + iw);
}

// raw (perm-order) token -> final-order token   (inverse of src(f)=win[f/4]*4+f%4)
__device__ __forceinline__ int dstrow_patch(int r) {
    int w4   = r & 3;
    int jraw = r >> 2;
    int gh = jraw / 24, gw = jraw % 24;
    int go = gh >> 2, ih = gh & 3, gwo = gw >> 2, iw = gw & 3;
    int b = ((go * 6 + gwo) * 4 + ih) * 4 + iw;
    return b * 4 + w4;
}

// ---------------------------------------------------------------------------
// Generic fp32 GEMM:  C[m][n] = act( A[m][:] . B[n][:] + bias[n] + resid[m][n] )
// B is (N x K) row-major (weights as stored).  Output row optionally remapped.
// 128x128 tile, BK=16, 256 threads, 8x8 micro-tile per thread.
// ---------------------------------------------------------------------------
#define BM 128
#define BN 128
#define BK 16
#define LDT (BM + 4)

__global__ __launch_bounds__(256) void gemm_bt(
    const float* __restrict__ A, int lda,
    const float* __restrict__ B, int ldb,
    const float* __restrict__ bias,
    const float* __restrict__ resid,
    float* __restrict__ C, int ldc,
    int M, int N, int K, int act, int rowmap)
{
    __shared__ float As[BK][LDT];
    __shared__ float Bs[BK][LDT];
    int tid = threadIdx.x;
    int x0 = blockIdx.x * BN, y0 = blockIdx.y * BM;
    int tx = tid & 15, ty = tid >> 4;
    int kl = tid & 15, rl = tid >> 4;

    float acc[8][8];
#pragma unroll
    for (int i = 0; i < 8; i++)
#pragma unroll
        for (int j = 0; j < 8; j++) acc[i][j] = 0.f;

    int ktiles = (K + BK - 1) / BK;
    for (int kt = 0; kt < ktiles; kt++) {
        int kg = kt * BK + kl;
        bool kin = kg < K;
#pragma unroll
        for (int it = 0; it < 8; it++) {
            int m = rl + it * 16;
            int gm = y0 + m;
            As[kl][m] = (kin && gm < M) ? A[(size_t)gm * lda + kg] : 0.f;
            int gn = x0 + m;
            Bs[kl][m] = (kin && gn < N) ? B[(size_t)gn * ldb + kg] : 0.f;
        }
        __syncthreads();
#pragma unroll
        for (int kk = 0; kk < BK; kk++) {
            float a[8], b[8];
#pragma unroll
            for (int j = 0; j < 8; j++) a[j] = As[kk][ty * 8 + j];
#pragma unroll
            for (int j = 0; j < 8; j++) b[j] = Bs[kk][tx * 8 + j];
#pragma unroll
            for (int i = 0; i < 8; i++)
#pragma unroll
                for (int j = 0; j < 8; j++) acc[i][j] = fmaf(a[i], b[j], acc[i][j]);
        }
        __syncthreads();
    }

#pragma unroll
    for (int i = 0; i < 8; i++) {
        int gm = y0 + ty * 8 + i;
        if (gm >= M) continue;
        int orow = gm;
        if (rowmap == 1) orow = dstrow_patch(gm);
        else if (rowmap == 2) orow = win_of(gm);
#pragma unroll
        for (int j = 0; j < 8; j++) {
            int gn = x0 + tx * 8 + j;
            if (gn >= N) continue;
            float v = acc[i][j];
            if (bias) v += bias[gn];
            if (resid) v += resid[(size_t)gm * ldc + gn];
            if (act == 1) v = 0.5f * v * (1.f + erff(v * 0.70710678118654752f)); // exact gelu
            C[(size_t)orow * ldc + gn] = v;
        }
    }
}

// ---------------------------------------------------------------------------
// RMSNorm over last dim 1280.  grid = rows, block = 256.
// ---------------------------------------------------------------------------
__global__ __launch_bounds__(256) void rmsnorm_k(const float* __restrict__ x,
                                                 const float* __restrict__ w,
                                                 float* __restrict__ out)
{
    int row = blockIdx.x, tid = threadIdx.x;
    const float* xr = x + (size_t)row * 1280;
    float ss = 0.f;
#pragma unroll
    for (int it = 0; it < 5; it++) { float v = xr[tid + it * 256]; ss += v * v; }
#pragma unroll
    for (int o = 32; o > 0; o >>= 1) ss += __shfl_xor(ss, o);
    __shared__ float wsum[4];
    if ((tid & 63) == 0) wsum[tid >> 6] = ss;
    __syncthreads();
    float tot = wsum[0] + wsum[1] + wsum[2] + wsum[3];
    float sc = rsqrtf(tot * (1.f / 1280.f) + 1e-6f);
#pragma unroll
    for (int it = 0; it < 5; it++) {
        int i = tid + it * 256;
        out[(size_t)row * 1280 + i] = xr[i] * sc * w[i];
    }
}

// ---------------------------------------------------------------------------
// RoPE in-place on qkv (S, 3*1280): rotates q and k. grid = tokens.
// ---------------------------------------------------------------------------
__global__ __launch_bounds__(256) void rope_k(float* __restrict__ qkv)
{
    int f = blockIdx.x;
    int b = f >> 2, w4 = f & 3;
    int wb = win_of(b);
    float hpos = (float)(2 * (wb / 24) + (w4 >> 1));
    float wpos = (float)(2 * (wb % 24) + (w4 & 1));
    for (int t = threadIdx.x; t < 640; t += 256) {
        int head = t / 40, d = t % 40;
        int i = d % 20;
        float invf = powf(10000.f, -(float)i * (1.f / 20.f));
        float ang = (d < 20 ? hpos : wpos) * invf;
        float c = cosf(ang), s = sinf(ang);
        float* qp = qkv + (size_t)f * 3840 + head * 80;
        float* kp = qp + 1280;
        float q0 = qp[d], q1 = qp[d + 40];
        qp[d]      = q0 * c - q1 * s;
        qp[d + 40] = q1 * c + q0 * s;
        float k0 = kp[d], k1 = kp[d + 40];
        kp[d]      = k0 * c - k1 * s;
        kp[d + 40] = k1 * c + k0 * s;
    }
}

// ---------------------------------------------------------------------------
// Attention: one block = (q-tile of 64 rows, head). Online softmax over K-tiles.
// full=0: only the matching window tile; full=1: all 36 tiles.
// Thread t: row = t>>2 owns cols {cgrp+4c} for scores, cols [cgrp*20,+20) for O.
// Ks stride 84 / Ps stride 65 chosen for conflict-free b128/broadcast access.
// ---------------------------------------------------------------------------
__global__ __launch_bounds__(256) void attn_k(const float* __restrict__ qkv,
                                              float* __restrict__ out, int full)
{
    int qt = blockIdx.x, head = blockIdx.y;
    __shared__ float Ks[64 * 84];
    __shared__ float Vs[64 * 80];
    __shared__ float Ps[64 * 65];
    int tid = threadIdx.x;
    int row = tid >> 2, cgrp = tid & 3;

    float4 qreg[20];
    const float4* qp = (const float4*)(qkv + (size_t)(qt * 64 + row) * 3840 + head * 80);
#pragma unroll
    for (int d = 0; d < 20; d++) qreg[d] = qp[d];

    float oc[20];
#pragma unroll
    for (int c = 0; c < 20; c++) oc[c] = 0.f;
    float m_i = -1e30f, l_i = 0.f;

    int kt0 = full ? 0 : qt, kte = full ? 36 : qt + 1;
    for (int kt = kt0; kt < kte; kt++) {
        __syncthreads();
        for (int i = tid; i < 64 * 20; i += 256) {
            int r = i / 20, d4 = i % 20;
            const float4* kg = (const float4*)(qkv + (size_t)(kt * 64 + r) * 3840 + 1280 + head * 80);
            const float4* vg = (const float4*)(qkv + (size_t)(kt * 64 + r) * 3840 + 2560 + head * 80);
            ((float4*)&Ks[r * 84])[d4] = kg[d4];
            ((float4*)&Vs[r * 80])[d4] = vg[d4];
        }
        __syncthreads();

        float sc[16];
        float tmax = -1e30f;
#pragma unroll
        for (int c = 0; c < 16; c++) {
            int col = cgrp + 4 * c;
            const float4* kp = (const float4*)&Ks[col * 84];
            float acc = 0.f;
#pragma unroll
            for (int d = 0; d < 20; d++) {
                float4 k4 = kp[d];
                acc += qreg[d].x * k4.x + qreg[d].y * k4.y + qreg[d].z * k4.z + qreg[d].w * k4.w;
            }
            sc[c] = acc * 0.11180339887498949f; // 80^-0.5
            tmax = fmaxf(tmax, sc[c]);
        }
        tmax = fmaxf(tmax, __shfl_xor(tmax, 1));
        tmax = fmaxf(tmax, __shfl_xor(tmax, 2));
        float mnew  = fmaxf(m_i, tmax);
        float alpha = __expf(m_i - mnew);
        float psum = 0.f;
#pragma unroll
        for (int c = 0; c < 16; c++) {
            float p = __expf(sc[c] - mnew);
            Ps[row * 65 + cgrp + 4 * c] = p;
            psum += p;
        }
        psum += __shfl_xor(psum, 1);
        psum += __shfl_xor(psum, 2);
        l_i = l_i * alpha + psum;
        m_i = mnew;
#pragma unroll
        for (int c = 0; c < 20; c++) oc[c] *= alpha;
        __syncthreads();

        for (int k = 0; k < 64; k++) {
            float p = Ps[row * 65 + k];
            const float4* vp = (const float4*)&Vs[k * 80 + cgrp * 20];
#pragma unroll
            for (int c4 = 0; c4 < 5; c4++) {
                float4 v4 = vp[c4];
                oc[c4 * 4 + 0] += p * v4.x;
                oc[c4 * 4 + 1] += p * v4.y;
                oc[c4 * 4 + 2] += p * v4.z;
                oc[c4 * 4 + 3] += p * v4.w;
            }
        }
    }

    float inv_l = 1.f / l_i;
    float* op = out + (size_t)(qt * 64 + row) * 1280 + head * 80 + cgrp * 20;
#pragma unroll
    for (int c = 0; c < 20; c++) op[c] = oc[c] * inv_l;
}

// ---------------------------------------------------------------------------
// g = silu(g) * u
// ---------------------------------------------------------------------------
__global__ void silu_mul_k(float* __restrict__ g, const float* __restrict__ u, int n)
{
    int i = blockIdx.x * 256 + threadIdx.x;
    if (i < n) {
        float gv = g[i], uv = u[i];
        g[i] = gv / (1.f + expf(-gv)) * uv;
    }
}

// ---------------------------------------------------------------------------
extern "C" void kernel_launch(void* const* d_in, const int* in_sizes, int n_in,
                              void* d_out, int out_size, void* d_ws, size_t ws_size,
                              hipStream_t stream)
{
    (void)in_sizes; (void)n_in; (void)out_size; (void)ws_size;
    const float* pixel   = (const float*)d_in[0];
    const float* patch_w = (const float*)d_in[1];
    const float* qkv_w   = (const float*)d_in[2];
    const float* qkv_b   = (const float*)d_in[3];
    const float* proj_w  = (const float*)d_in[4];
    const float* proj_b  = (const float*)d_in[5];
    const float* norm1_w = (const float*)d_in[6];
    const float* norm2_w = (const float*)d_in[7];
    const float* gate_w  = (const float*)d_in[8];
    const float* gate_b  = (const float*)d_in[9];
    const float* up_w    = (const float*)d_in[10];
    const float* up_b    = (const float*)d_in[11];
    const float* down_w  = (const float*)d_in[12];
    const float* down_b  = (const float*)d_in[13];
    const float* ln_q_w  = (const float*)d_in[14];
    const float* m1_w    = (const float*)d_in[15];
    const float* m1_b    = (const float*)d_in[16];
    const float* m2_w    = (const float*)d_in[17];
    const float* m2_b    = (const float*)d_in[18];
    float* out = (float*)d_out;

    float* ws   = (float*)d_ws;
    float* xbuf = ws;                                  // 2304*1280
    float* hbuf = xbuf + (size_t)N_TOK * 1280;         // 2304*1280
    float* qkvb = hbuf + (size_t)N_TOK * 1280;         // 2304*3840
    float* Gbuf = qkvb + (size_t)N_TOK * 3840;         // 2304*3420
    float* Ubuf = qkvb;                                // reuse (qkv dead after attn)

    auto gemm = [&](const float* A, int lda, const float* B, int ldb,
                    const float* bias, const float* resid,
                    float* C, int ldc, int M, int N, int K, int act, int rowmap) {
        dim3 g((N + BN - 1) / BN, (M + BM - 1) / BM);
        gemm_bt<<<g, dim3(256), 0, stream>>>(A, lda, B, ldb, bias, resid, C, ldc,
                                             M, N, K, act, rowmap);
    };

    // patch embed, scattered into final token order
    gemm(pixel, 1176, patch_w, 1176, nullptr, nullptr, xbuf, 1280,
         N_TOK, 1280, 1176, 0, 1);

    for (int i = 0; i < 8; i++) {
        const float* qw = qkv_w  + (size_t)i * 3840 * 1280;
        const float* pw = proj_w + (size_t)i * 1280 * 1280;
        const float* gw = gate_w + (size_t)i * 3420 * 1280;
        const float* uw = up_w   + (size_t)i * 3420 * 1280;
        const float* dw = down_w + (size_t)i * 1280 * 3420;

        rmsnorm_k<<<N_TOK, 256, 0, stream>>>(xbuf, norm1_w + i * 1280, hbuf);
        gemm(hbuf, 1280, qw, 1280, qkv_b + (size_t)i * 3840, nullptr, qkvb, 3840,
             N_TOK, 3840, 1280, 0, 0);
        rope_k<<<N_TOK, 256, 0, stream>>>(qkvb);
        int full = (i == 3 || i == 7) ? 1 : 0;
        attn_k<<<dim3(36, 16), dim3(256), 0, stream>>>(qkvb, hbuf, full);
        gemm(hbuf, 1280, pw, 1280, proj_b + (size_t)i * 1280, xbuf, xbuf, 1280,
             N_TOK, 1280, 1280, 0, 0);

        rmsnorm_k<<<N_TOK, 256, 0, stream>>>(xbuf, norm2_w + i * 1280, hbuf);
        gemm(hbuf, 1280, gw, 1280, gate_b + (size_t)i * 3420, nullptr, Gbuf, 3420,
             N_TOK, 3420, 1280, 0, 0);
        gemm(hbuf, 1280, uw, 1280, up_b + (size_t)i * 3420, nullptr, Ubuf, 3420,
             N_TOK, 3420, 1280, 0, 0);
        int nGU = N_TOK * 3420;
        silu_mul_k<<<(nGU + 255) / 256, dim3(256), 0, stream>>>(Gbuf, Ubuf, nGU);
        gemm(Gbuf, 3420, dw, 3420, down_b + (size_t)i * 1280, xbuf, xbuf, 1280,
             N_TOK, 1280, 3420, 0, 0);
    }

    // final merger MLP: rmsnorm -> (576,5120) -> gelu(m1) -> m2 -> scatter rows by win
    rmsnorm_k<<<N_TOK, 256, 0, stream>>>(xbuf, ln_q_w, hbuf);
    gemm(hbuf, 5120, m1_w, 5120, m1_b, nullptr, Gbuf, 5120, 576, 5120, 5120, 1, 0);
    gemm(Gbuf, 5120, m2_w, 5120, m2_b, nullptr, out, 3584, 576, 3584, 5120, 0, 2);
}

// Round 2
// 10236.476 us; speedup vs baseline: 3.4360x; 3.4360x over previous
//
#include <hip/hip_runtime.h>
#include <math.h>

// ---------------------------------------------------------------------------
// Qwen2.5-Vision block on MI355X — round 2: bf16-MFMA GEMMs, fp32 elsewhere.
// S=2304 tokens, HID=1280, 16 heads x 80, 8 layers, window(64)/full attn,
// SwiGLU MLP (3420), final 2x2-merge MLP 5120->5120(gelu)->3584.
// ---------------------------------------------------------------------------

#define N_TOK 2304

typedef __bf16 bf16x4 __attribute__((ext_vector_type(4)));
typedef __bf16 bf16x8 __attribute__((ext_vector_type(8)));
typedef float floatx4 __attribute__((ext_vector_type(4)));

// perm-order block id for final-order block j  (win[j])
__device__ __forceinline__ int win_of(int j) {
    int iw  = j & 3;
    int ih  = (j >> 2) & 3;
    int gwo = (j >> 4) % 6;
    int go  = j / 96;
    return (go * 4 + ih) * 24 + (gwo * 4 + iw);
}

// raw (perm-order) token -> final-order token
__device__ __forceinline__ int dstrow_patch(int r) {
    int w4   = r & 3;
    int jraw = r >> 2;
    int gh = jraw / 24, gw = jraw % 24;
    int go = gh >> 2, ih = gh & 3, gwo = gw >> 2, iw = gw & 3;
    int b = ((go * 6 + gwo) * 4 + ih) * 4 + iw;
    return b * 4 + w4;
}

// ---------------------------------------------------------------------------
// bf16 MFMA GEMM:  C[m][n] = epi( A[m][:].B[n][:] + bias[n] + resid )
// A (M x K) fp32 row-major, B (N x K) fp32 row-major (weights as stored).
// fp32 -> bf16 conversion happens during LDS staging. fp32 accumulate.
// 128x128 tile, BK=32, 256 thr (4 waves 2x2), wave = 64x64 = 4x4 mfma tiles.
// act: 0=none, 1=exact gelu.  mulgate: if set, v = silu(mulgate[m][n]) * v.
// rowmap: 0 none, 1 patch scatter, 2 win scatter.
// ---------------------------------------------------------------------------
#define BM 128
#define BN 128
#define BK 32
#define LDSS 40   // row stride in bf16 (80 B) -> <=2-way LDS aliasing

__global__ __launch_bounds__(256) void gemm_mfma(
    const float* __restrict__ A, int lda,
    const float* __restrict__ B, int ldb,
    const float* __restrict__ bias,
    const float* __restrict__ resid,
    const float* __restrict__ mulgate,
    float* __restrict__ C, int ldc,
    int M, int N, int K, int act, int rowmap)
{
    __shared__ __bf16 As[BM][LDSS];
    __shared__ __bf16 Bs[BN][LDSS];

    int tid  = threadIdx.x;
    int lane = tid & 63;
    int w    = tid >> 6;
    int wm = w & 1, wn = w >> 1;
    int l15 = lane & 15, lq = lane >> 4;
    int x0 = blockIdx.x * BN, y0 = blockIdx.y * BM;

    floatx4 acc[4][4] = {};

    int r0 = tid >> 3;        // 0..31
    int kc = (tid & 7) * 4;   // 0,4,...,28

    for (int k0 = 0; k0 < K; k0 += BK) {
        int kg = k0 + kc;
#pragma unroll
        for (int it = 0; it < 4; it++) {
            int row = r0 + it * 32;
            int gm = y0 + row, gn = x0 + row;
            float ax = 0.f, ay = 0.f, az = 0.f, aw = 0.f;
            float bx = 0.f, by = 0.f, bz = 0.f, bw = 0.f;
            if (kg + 3 < K) {
                if (gm < M) {
                    float4 v = *(const float4*)&A[(size_t)gm * lda + kg];
                    ax = v.x; ay = v.y; az = v.z; aw = v.w;
                }
                if (gn < N) {
                    float4 v = *(const float4*)&B[(size_t)gn * ldb + kg];
                    bx = v.x; by = v.y; bz = v.z; bw = v.w;
                }
            } else if (kg < K) {
                float ta[4] = {0, 0, 0, 0}, tb[4] = {0, 0, 0, 0};
                for (int u = 0; u < 4; u++)
                    if (kg + u < K) {
                        if (gm < M) ta[u] = A[(size_t)gm * lda + kg + u];
                        if (gn < N) tb[u] = B[(size_t)gn * ldb + kg + u];
                    }
                ax = ta[0]; ay = ta[1]; az = ta[2]; aw = ta[3];
                bx = tb[0]; by = tb[1]; bz = tb[2]; bw = tb[3];
            }
            bf16x4 a4 = { (__bf16)ax, (__bf16)ay, (__bf16)az, (__bf16)aw };
            bf16x4 b4 = { (__bf16)bx, (__bf16)by, (__bf16)bz, (__bf16)bw };
            *(bf16x4*)&As[row][kc] = a4;
            *(bf16x4*)&Bs[row][kc] = b4;
        }
        __syncthreads();

        bf16x8 af[4], bfr[4];
#pragma unroll
        for (int i = 0; i < 4; i++)
            af[i] = *(const bf16x8*)&As[wm * 64 + i * 16 + l15][lq * 8];
#pragma unroll
        for (int j = 0; j < 4; j++)
            bfr[j] = *(const bf16x8*)&Bs[wn * 64 + j * 16 + l15][lq * 8];
#pragma unroll
        for (int i = 0; i < 4; i++)
#pragma unroll
            for (int j = 0; j < 4; j++)
                acc[i][j] = __builtin_amdgcn_mfma_f32_16x16x32_bf16(
                    af[i], bfr[j], acc[i][j], 0, 0, 0);
        __syncthreads();
    }

#pragma unroll
    for (int i = 0; i < 4; i++) {
#pragma unroll
        for (int r = 0; r < 4; r++) {
            int gm = y0 + wm * 64 + i * 16 + lq * 4 + r;
            if (gm >= M) continue;
            int orow = gm;
            if (rowmap == 1) orow = dstrow_patch(gm);
            else if (rowmap == 2) orow = win_of(gm);
#pragma unroll
            for (int j = 0; j < 4; j++) {
                int gn = x0 + wn * 64 + j * 16 + l15;
                if (gn >= N) continue;
                float v = acc[i][j][r];
                if (bias) v += bias[gn];
                if (resid) v += resid[(size_t)gm * ldc + gn];
                if (mulgate) {
                    float g = mulgate[(size_t)gm * ldc + gn];
                    v = g / (1.f + __expf(-g)) * v;
                }
                if (act == 1) v = 0.5f * v * (1.f + erff(v * 0.70710678118654752f));
                C[(size_t)orow * ldc + gn] = v;
            }
        }
    }
}

// ---------------------------------------------------------------------------
// RMSNorm over last dim 1280.  grid = rows, block = 256.
// ---------------------------------------------------------------------------
__global__ __launch_bounds__(256) void rmsnorm_k(const float* __restrict__ x,
                                                 const float* __restrict__ w,
                                                 float* __restrict__ out)
{
    int row = blockIdx.x, tid = threadIdx.x;
    const float* xr = x + (size_t)row * 1280;
    float ss = 0.f;
#pragma unroll
    for (int it = 0; it < 5; it++) { float v = xr[tid + it * 256]; ss += v * v; }
#pragma unroll
    for (int o = 32; o > 0; o >>= 1) ss += __shfl_xor(ss, o);
    __shared__ float wsum[4];
    if ((tid & 63) == 0) wsum[tid >> 6] = ss;
    __syncthreads();
    float tot = wsum[0] + wsum[1] + wsum[2] + wsum[3];
    float sc = rsqrtf(tot * (1.f / 1280.f) + 1e-6f);
#pragma unroll
    for (int it = 0; it < 5; it++) {
        int i = tid + it * 256;
        out[(size_t)row * 1280 + i] = xr[i] * sc * w[i];
    }
}

// ---------------------------------------------------------------------------
// RoPE in-place on qkv (S, 3*1280): rotates q and k. grid = tokens.
// ---------------------------------------------------------------------------
__global__ __launch_bounds__(256) void rope_k(float* __restrict__ qkv)
{
    int f = blockIdx.x;
    int b = f >> 2, w4 = f & 3;
    int wb = win_of(b);
    float hpos = (float)(2 * (wb / 24) + (w4 >> 1));
    float wpos = (float)(2 * (wb % 24) + (w4 & 1));
    for (int t = threadIdx.x; t < 640; t += 256) {
        int head = t / 40, d = t % 40;
        int i = d % 20;
        float invf = powf(10000.f, -(float)i * (1.f / 20.f));
        float ang = (d < 20 ? hpos : wpos) * invf;
        float c = cosf(ang), s = sinf(ang);
        float* qp = qkv + (size_t)f * 3840 + head * 80;
        float* kp = qp + 1280;
        float q0 = qp[d], q1 = qp[d + 40];
        qp[d]      = q0 * c - q1 * s;
        qp[d + 40] = q1 * c + q0 * s;
        float k0 = kp[d], k1 = kp[d + 40];
        kp[d]      = k0 * c - k1 * s;
        kp[d + 40] = k1 * c + k0 * s;
    }
}

// ---------------------------------------------------------------------------
// Attention: one block = (q-tile of 64 rows, head). Online softmax over K-tiles.
// ---------------------------------------------------------------------------
__global__ __launch_bounds__(256) void attn_k(const float* __restrict__ qkv,
                                              float* __restrict__ out, int full)
{
    int qt = blockIdx.x, head = blockIdx.y;
    __shared__ float Ks[64 * 84];
    __shared__ float Vs[64 * 80];
    __shared__ float Ps[64 * 65];
    int tid = threadIdx.x;
    int row = tid >> 2, cgrp = tid & 3;

    float4 qreg[20];
    const float4* qp = (const float4*)(qkv + (size_t)(qt * 64 + row) * 3840 + head * 80);
#pragma unroll
    for (int d = 0; d < 20; d++) qreg[d] = qp[d];

    float oc[20];
#pragma unroll
    for (int c = 0; c < 20; c++) oc[c] = 0.f;
    float m_i = -1e30f, l_i = 0.f;

    int kt0 = full ? 0 : qt, kte = full ? 36 : qt + 1;
    for (int kt = kt0; kt < kte; kt++) {
        __syncthreads();
        for (int i = tid; i < 64 * 20; i += 256) {
            int r = i / 20, d4 = i % 20;
            const float4* kg = (const float4*)(qkv + (size_t)(kt * 64 + r) * 3840 + 1280 + head * 80);
            const float4* vg = (const float4*)(qkv + (size_t)(kt * 64 + r) * 3840 + 2560 + head * 80);
            ((float4*)&Ks[r * 84])[d4] = kg[d4];
            ((float4*)&Vs[r * 80])[d4] = vg[d4];
        }
        __syncthreads();

        float sc[16];
        float tmax = -1e30f;
#pragma unroll
        for (int c = 0; c < 16; c++) {
            int col = cgrp + 4 * c;
            const float4* kp = (const float4*)&Ks[col * 84];
            float acc = 0.f;
#pragma unroll
            for (int d = 0; d < 20; d++) {
                float4 k4 = kp[d];
                acc += qreg[d].x * k4.x + qreg[d].y * k4.y + qreg[d].z * k4.z + qreg[d].w * k4.w;
            }
            sc[c] = acc * 0.11180339887498949f; // 80^-0.5
            tmax = fmaxf(tmax, sc[c]);
        }
        tmax = fmaxf(tmax, __shfl_xor(tmax, 1));
        tmax = fmaxf(tmax, __shfl_xor(tmax, 2));
        float mnew  = fmaxf(m_i, tmax);
        float alpha = __expf(m_i - mnew);
        float psum = 0.f;
#pragma unroll
        for (int c = 0; c < 16; c++) {
            float p = __expf(sc[c] - mnew);
            Ps[row * 65 + cgrp + 4 * c] = p;
            psum += p;
        }
        psum += __shfl_xor(psum, 1);
        psum += __shfl_xor(psum, 2);
        l_i = l_i * alpha + psum;
        m_i = mnew;
#pragma unroll
        for (int c = 0; c < 20; c++) oc[c] *= alpha;
        __syncthreads();

        for (int k = 0; k < 64; k++) {
            float p = Ps[row * 65 + k];
            const float4* vp = (const float4*)&Vs[k * 80 + cgrp * 20];
#pragma unroll
            for (int c4 = 0; c4 < 5; c4++) {
                float4 v4 = vp[c4];
                oc[c4 * 4 + 0] += p * v4.x;
                oc[c4 * 4 + 1] += p * v4.y;
                oc[c4 * 4 + 2] += p * v4.z;
                oc[c4 * 4 + 3] += p * v4.w;
            }
        }
    }

    float inv_l = 1.f / l_i;
    float* op = out + (size_t)(qt * 64 + row) * 1280 + head * 80 + cgrp * 20;
#pragma unroll
    for (int c = 0; c < 20; c++) op[c] = oc[c] * inv_l;
}

// ---------------------------------------------------------------------------
extern "C" void kernel_launch(void* const* d_in, const int* in_sizes, int n_in,
                              void* d_out, int out_size, void* d_ws, size_t ws_size,
                              hipStream_t stream)
{
    (void)in_sizes; (void)n_in; (void)out_size; (void)ws_size;
    const float* pixel   = (const float*)d_in[0];
    const float* patch_w = (const float*)d_in[1];
    const float* qkv_w   = (const float*)d_in[2];
    const float* qkv_b   = (const float*)d_in[3];
    const float* proj_w  = (const float*)d_in[4];
    const float* proj_b  = (const float*)d_in[5];
    const float* norm1_w = (const float*)d_in[6];
    const float* norm2_w = (const float*)d_in[7];
    const float* gate_w  = (const float*)d_in[8];
    const float* gate_b  = (const float*)d_in[9];
    const float* up_w    = (const float*)d_in[10];
    const float* up_b    = (const float*)d_in[11];
    const float* down_w  = (const float*)d_in[12];
    const float* down_b  = (const float*)d_in[13];
    const float* ln_q_w  = (const float*)d_in[14];
    const float* m1_w    = (const float*)d_in[15];
    const float* m1_b    = (const float*)d_in[16];
    const float* m2_w    = (const float*)d_in[17];
    const float* m2_b    = (const float*)d_in[18];
    float* out = (float*)d_out;

    float* ws   = (float*)d_ws;
    float* xbuf = ws;                                  // 2304*1280
    float* hbuf = xbuf + (size_t)N_TOK * 1280;         // 2304*1280
    float* qkvb = hbuf + (size_t)N_TOK * 1280;         // 2304*3840
    float* Gbuf = qkvb + (size_t)N_TOK * 3840;         // 2304*3420
    float* Ubuf = qkvb;                                // reuse (qkv dead after attn)

    auto gemm = [&](const float* A, int lda, const float* B, int ldb,
                    const float* bias, const float* resid, const float* mulgate,
                    float* C, int ldc, int M, int N, int K, int act, int rowmap) {
        dim3 g((N + BN - 1) / BN, (M + BM - 1) / BM);
        gemm_mfma<<<g, dim3(256), 0, stream>>>(A, lda, B, ldb, bias, resid, mulgate,
                                               C, ldc, M, N, K, act, rowmap);
    };

    // patch embed, scattered into final token order
    gemm(pixel, 1176, patch_w, 1176, nullptr, nullptr, nullptr, xbuf, 1280,
         N_TOK, 1280, 1176, 0, 1);

    for (int i = 0; i < 8; i++) {
        const float* qw = qkv_w  + (size_t)i * 3840 * 1280;
        const float* pw = proj_w + (size_t)i * 1280 * 1280;
        const float* gw = gate_w + (size_t)i * 3420 * 1280;
        const float* uw = up_w   + (size_t)i * 3420 * 1280;
        const float* dw = down_w + (size_t)i * 1280 * 3420;

        rmsnorm_k<<<N_TOK, 256, 0, stream>>>(xbuf, norm1_w + i * 1280, hbuf);
        gemm(hbuf, 1280, qw, 1280, qkv_b + (size_t)i * 3840, nullptr, nullptr,
             qkvb, 3840, N_TOK, 3840, 1280, 0, 0);
        rope_k<<<N_TOK, 256, 0, stream>>>(qkvb);
        int full = (i == 3 || i == 7) ? 1 : 0;
        attn_k<<<dim3(36, 16), dim3(256), 0, stream>>>(qkvb, hbuf, full);
        gemm(hbuf, 1280, pw, 1280, proj_b + (size_t)i * 1280, xbuf, nullptr,
             xbuf, 1280, N_TOK, 1280, 1280, 0, 0);

        rmsnorm_k<<<N_TOK, 256, 0, stream>>>(xbuf, norm2_w + i * 1280, hbuf);
        // gate GEMM (no act), then up GEMM with fused silu(gate)*up epilogue
        gemm(hbuf, 1280, gw, 1280, gate_b + (size_t)i * 3420, nullptr, nullptr,
             Gbuf, 3420, N_TOK, 3420, 1280, 0, 0);
        gemm(hbuf, 1280, uw, 1280, up_b + (size_t)i * 3420, nullptr, Gbuf,
             Ubuf, 3420, N_TOK, 3420, 1280, 0, 0);
        gemm(Ubuf, 3420, dw, 3420, down_b + (size_t)i * 1280, xbuf, nullptr,
             xbuf, 1280, N_TOK, 1280, 3420, 0, 0);
    }

    // final merger MLP: rmsnorm -> (576,5120) -> gelu(m1) -> m2 -> scatter rows
    rmsnorm_k<<<N_TOK, 256, 0, stream>>>(xbuf, ln_q_w, hbuf);
    gemm(hbuf, 5120, m1_w, 5120, m1_b, nullptr, nullptr, Gbuf, 5120,
         576, 5120, 5120, 1, 0);
    gemm(Gbuf, 5120, m2_w, 5120, m2_b, nullptr, nullptr, out, 3584,
         576, 3584, 5120, 0, 2);
}